// Round 1
// baseline (150.641 us; speedup 1.0000x reference)
//
#include <hip/hip_runtime.h>
#include <stdint.h>

// Rule 110 CA, batch=32, width=16384, 64 iterations, zero-padded boundaries.
// Reference indexing: idx = L*1 + C*2 + R*4, lookup[k] = (110 >> k) & 1.
// Truth table reduces to: new = (L | C) & ~(L & C & R).
//
// Phase 1: one wave per batch row; row = 256 uint64 words, 4 words/lane.
//          Cross-lane 1-bit carries via __ballot (SGPR broadcast, no LDS).
//          Writes all 65 packed states to d_ws (32*65*256*8 B = 4.25 MB).
// Phase 2: massively parallel unpack: each thread emits one int4 (4 cells),
//          perfectly coalesced 16 B/lane stores. 136 MB written -> HBM-bound.

#define WIDTH   16384
#define BATCH   32
#define ITERS   64
#define WORDS64 (WIDTH / 64)   // 256 uint64 per row
#define WPL     4              // words per lane (64 lanes * 4 = 256)

__global__ __launch_bounds__(64) void ca_steps_kernel(
    const float* __restrict__ x, uint64_t* __restrict__ packed)
{
    const int b    = blockIdx.x;   // batch row
    const int lane = threadIdx.x;  // 0..63

    const float* xb = x + (size_t)b * WIDTH;

    // ---- pack initial state: lane owns cells [lane*256, lane*256+256) ----
    uint64_t c[WPL];
    const float4* xv = (const float4*)(xb + lane * 256);
    #pragma unroll
    for (int k = 0; k < WPL; ++k) {
        uint64_t m = 0;
        #pragma unroll
        for (int i = 0; i < 16; ++i) {
            float4 f = xv[k * 16 + i];
            m |= (uint64_t)(f.x >= 0.5f) << (i * 4 + 0);
            m |= (uint64_t)(f.y >= 0.5f) << (i * 4 + 1);
            m |= (uint64_t)(f.z >= 0.5f) << (i * 4 + 2);
            m |= (uint64_t)(f.w >= 0.5f) << (i * 4 + 3);
        }
        c[k] = m;
    }

    // packed layout: [b][t][WORDS64 uint64]
    uint64_t* pb = packed + ((size_t)b * (ITERS + 1)) * WORDS64 + (size_t)lane * WPL;

    // store state0 (t = 0)
    #pragma unroll
    for (int k = 0; k < WPL; ++k) pb[k] = c[k];

    // ---- 64 CA steps, all in registers ----
    for (int t = 1; t <= ITERS; ++t) {
        // A: bit l = LSB of lane l's c[0]; B: bit l = MSB of lane l's c[3]
        uint64_t A = __ballot((c[0] & 1ull) != 0);
        uint64_t B = __ballot((c[WPL - 1] >> 63) != 0);
        // left-in bit for this lane = bit (lane-1) of B (0 at lane 0)
        uint64_t carryL = ((B << 1) >> lane) & 1ull;
        // right-in bit for this lane = bit (lane+1) of A (0 at lane 63)
        uint64_t carryR = ((A >> 1) >> lane) & 1ull;

        uint64_t l0 = (c[0] << 1) | carryL;
        uint64_t l1 = (c[1] << 1) | (c[0] >> 63);
        uint64_t l2 = (c[2] << 1) | (c[1] >> 63);
        uint64_t l3 = (c[3] << 1) | (c[2] >> 63);

        uint64_t r0 = (c[0] >> 1) | (c[1] << 63);
        uint64_t r1 = (c[1] >> 1) | (c[2] << 63);
        uint64_t r2 = (c[2] >> 1) | (c[3] << 63);
        uint64_t r3 = (c[3] >> 1) | (carryR << 63);

        // new = (L | C) & ~(L & C & R)
        c[0] = (l0 | c[0]) & ~(l0 & c[0] & r0);
        c[1] = (l1 | c[1]) & ~(l1 & c[1] & r1);
        c[2] = (l2 | c[2]) & ~(l2 & c[2] & r2);
        c[3] = (l3 | c[3]) & ~(l3 & c[3] & r3);

        uint64_t* pt = pb + (size_t)t * WORDS64;
        #pragma unroll
        for (int k = 0; k < WPL; ++k) pt[k] = c[k];
    }
}

__global__ __launch_bounds__(256) void unpack_kernel(
    const uint32_t* __restrict__ packed, int4* __restrict__ out, int n4)
{
    int g = blockIdx.x * 256 + threadIdx.x;
    if (g >= n4) return;
    // int4 g covers flat output cells [4g, 4g+4) -> bits [(g&7)*4 ..) of u32 word g/8
    uint32_t w   = packed[g >> 3];
    uint32_t nib = w >> ((g & 7) * 4);
    out[g] = make_int4((int)(nib & 1u), (int)((nib >> 1) & 1u),
                       (int)((nib >> 2) & 1u), (int)((nib >> 3) & 1u));
}

extern "C" void kernel_launch(void* const* d_in, const int* in_sizes, int n_in,
                              void* d_out, int out_size, void* d_ws, size_t ws_size,
                              hipStream_t stream)
{
    const float* x = (const float*)d_in[0];
    // d_in[1] = lookup (rule 110 table) -- rule is fixed by setup, baked into logic.

    uint64_t* packed = (uint64_t*)d_ws;  // needs 32*65*256*8 = 4,259,840 bytes

    ca_steps_kernel<<<BATCH, 64, 0, stream>>>(x, packed);

    const int n4 = BATCH * (ITERS + 1) * (WIDTH / 4);  // 8,519,680 int4 stores
    unpack_kernel<<<(n4 + 255) / 256, 256, 0, stream>>>(
        (const uint32_t*)d_ws, (int4*)d_out, n4);
}

// Round 2
// 137.496 us; speedup vs baseline: 1.0956x; 1.0956x over previous
//
#include <hip/hip_runtime.h>
#include <stdint.h>

// Rule 110 CA, batch=32, width=16384, 64 iterations, zero boundaries each step.
// idx = L + 2C + 4R, lookup[k]=(110>>k)&1  ==>  new = (L | C) & ~(L & C & R).
//
// Fused single kernel, trapezoidal width tiling:
//   - one wave per (batch row, 1024-cell output tile); 512 waves total (2/CU)
//   - working state = 2048 bits = 1 uint32 per lane, covering [s-64, s+1984)
//   - halo arithmetic: at step t we need working bits [t, 1152-t) valid;
//     left-edge staleness reaches w<=t-1, right-edge w>=2048-t -> both safe.
//   - cross-lane 1-bit carries via __ballot (no LDS for the CA itself)
//   - each step: bounce state through 256B LDS to redistribute bits to the
//     lanes that store them, then 4 coalesced global_store_dwordx4 per lane
//     group -> 4 KB/wave/step, 136 MB total = the HBM-write floor.

#define WIDTH 16384
#define BATCH 32
#define ITERS 64
#define TILE  1024
#define NTILE (WIDTH / TILE)   // 16

__global__ __launch_bounds__(64) void ca_fused_kernel(
    const float* __restrict__ x, int* __restrict__ out)
{
    const int lane = threadIdx.x;          // 0..63
    const int tile = blockIdx.x;           // 0..15
    const int b    = blockIdx.y;           // 0..31
    const int s    = tile * TILE;          // output tile start cell

    __shared__ uint32_t sh[64];

    // ---- pack initial state: lane owns working bits [lane*32, lane*32+32),
    //      i.e. global positions [s-64+lane*32, +32). Boundaries align to lanes.
    const int p0 = s - 64 + lane * 32;
    const bool valid = (p0 >= 0) && (p0 < WIDTH);
    const uint32_t vmask = valid ? 0xffffffffu : 0u;

    uint32_t c = 0;
    if (valid) {
        const float4* xv = (const float4*)(x + (size_t)b * WIDTH + p0);
        #pragma unroll
        for (int i = 0; i < 8; ++i) {
            float4 f = xv[i];
            c |= (uint32_t)(f.x >= 0.5f) << (i * 4 + 0);
            c |= (uint32_t)(f.y >= 0.5f) << (i * 4 + 1);
            c |= (uint32_t)(f.z >= 0.5f) << (i * 4 + 2);
            c |= (uint32_t)(f.w >= 0.5f) << (i * 4 + 3);
        }
    }

    // output base for (b, t=0), this tile
    int* outb = out + ((size_t)b * (ITERS + 1)) * WIDTH + s;

    for (int t = 0; t <= ITERS; ++t) {
        // ---- unpack current state -> 1024 int32, coalesced int4 stores ----
        sh[lane] = c;
        __syncthreads();
        int4* ov = (int4*)outb;
        #pragma unroll
        for (int j = 0; j < 4; ++j) {
            // store j, lane i covers output cells (j*64+i)*4 .. +4 of the tile
            // = working bits 64 + j*256 + i*4
            uint32_t w   = sh[2 + j * 8 + (lane >> 3)];
            uint32_t nib = w >> ((lane & 7) * 4);
            ov[j * 64 + lane] = make_int4((int)(nib & 1u), (int)((nib >> 1) & 1u),
                                          (int)((nib >> 2) & 1u), (int)((nib >> 3) & 1u));
        }
        __syncthreads();   // single-wave block: near-free; protects LDS WAR
        outb += WIDTH;
        if (t == ITERS) break;

        // ---- one CA step, cross-lane carries via 64-bit ballots ----
        uint64_t A  = __ballot((c & 1u) != 0);         // bit l = LSB of lane l
        uint64_t Bm = __ballot((c >> 31) != 0);        // bit l = MSB of lane l
        uint32_t carryL = (uint32_t)(((Bm << 1) >> lane) & 1ull); // MSB of lane-1
        uint32_t carryR = (uint32_t)(((A  >> 1) >> lane) & 1ull); // LSB of lane+1

        uint32_t l = (c << 1) | carryL;
        uint32_t r = (c >> 1) | (carryR << 31);
        c = ((l | c) & ~(l & c & r)) & vmask;  // vmask: out-of-array stays 0
    }
}

extern "C" void kernel_launch(void* const* d_in, const int* in_sizes, int n_in,
                              void* d_out, int out_size, void* d_ws, size_t ws_size,
                              hipStream_t stream)
{
    const float* x = (const float*)d_in[0];
    // d_in[1] = lookup table for rule 110 -- fixed by setup, baked into logic.
    (void)d_ws; (void)ws_size;

    dim3 grid(NTILE, BATCH);   // 16 x 32 = 512 single-wave blocks
    ca_fused_kernel<<<grid, 64, 0, stream>>>(x, (int*)d_out);
}